// Round 5
// baseline (118.163 us; speedup 1.0000x reference)
//
#include <hip/hip_runtime.h>

#define NN 4096
#define MM 4096
#define NEG 0.01f

// ATTRIBUTION PROBE ROUND: identical kernel launched TWICE (idempotent,
// same work every call). dur_us delta vs the single-launch round == true
// kernel duration, which never shows in the top-5 dispatch table.
__global__ __launch_bounds__(256, 4) void abstract_leaky_relu_kernel(
    const float* __restrict__ lbnd,
    const float* __restrict__ ubnd,
    const float* __restrict__ alpha,
    const float* __restrict__ W,
    const float* __restrict__ b,
    const float* __restrict__ l0,
    const float* __restrict__ u0,
    float* __restrict__ out)
{
    __shared__ float s_c[MM];
    __shared__ float s_r[MM];

    for (int j = threadIdx.x * 4; j < MM; j += 256 * 4) {
        const float4 l = *(const float4*)(l0 + j);
        const float4 u = *(const float4*)(u0 + j);
        *(float4*)(s_c + j) = make_float4(0.5f*(l.x+u.x), 0.5f*(l.y+u.y),
                                          0.5f*(l.z+u.z), 0.5f*(l.w+u.w));
        *(float4*)(s_r + j) = make_float4(0.5f*(u.x-l.x), 0.5f*(u.y-l.y),
                                          0.5f*(u.z-l.z), 0.5f*(u.w-l.w));
    }
    __syncthreads();

    const int wave = threadIdx.x >> 6;
    const int lane = threadIdx.x & 63;
    const int row  = (blockIdx.x << 2) + wave;

    const float* __restrict__ Wr = W + (size_t)row * MM;
    const int base = lane * 4;

    float s1a = 0.f, s1b = 0.f, s2a = 0.f, s2b = 0.f;

    #pragma unroll
    for (int t = 0; t < 16; ++t) {
        const int j = base + t * 256;
        const float4 w = *(const float4*)(Wr + j);
        const float4 c = *(const float4*)(s_c + j);
        const float4 r = *(const float4*)(s_r + j);
        if (t & 1) {
            s1b += w.x * c.x + w.y * c.y + w.z * c.z + w.w * c.w;
            s2b += fabsf(w.x) * r.x + fabsf(w.y) * r.y +
                   fabsf(w.z) * r.z + fabsf(w.w) * r.w;
        } else {
            s1a += w.x * c.x + w.y * c.y + w.z * c.z + w.w * c.w;
            s2a += fabsf(w.x) * r.x + fabsf(w.y) * r.y +
                   fabsf(w.z) * r.z + fabsf(w.w) * r.w;
        }
    }

    float s1 = s1a + s1b;
    float s2 = s2a + s2b;

    #pragma unroll
    for (int off = 32; off > 0; off >>= 1) {
        s1 += __shfl_down(s1, off);
        s2 += __shfl_down(s2, off);
    }

    if (lane == 0) {
        const float L = lbnd[row];
        const float U = ubnd[row];
        const float A = alpha[row];
        const float B = b[row];

        float lw = NEG, uw = NEG, ub_bias = 0.0f;
        if (L > 0.0f) {
            lw = 1.0f; uw = 1.0f;
        } else if (L < 0.0f && U > 0.0f) {
            const float slope = (U - NEG * L) / (U - L);
            uw = slope;
            ub_bias = (NEG - slope) * L;   // crossing-neuron upper intercept
            lw = fminf(fmaxf(A, NEG), 1.0f);
        }

        const float Pu = s1 + s2;   // max(W,0)@u0 + min(W,0)@l0
        const float Pl = s1 - s2;   // max(W,0)@l0 + min(W,0)@u0
        out[row]      = lw * (Pl + B);             // lower
        out[NN + row] = uw * (Pu + B) + ub_bias;   // upper
    }
}

extern "C" void kernel_launch(void* const* d_in, const int* in_sizes, int n_in,
                              void* d_out, int out_size, void* d_ws, size_t ws_size,
                              hipStream_t stream) {
    const float* lbnd  = (const float*)d_in[0];
    const float* ubnd  = (const float*)d_in[1];
    const float* alpha = (const float*)d_in[2];
    const float* W     = (const float*)d_in[3];
    const float* b     = (const float*)d_in[4];
    const float* l0    = (const float*)d_in[5];
    const float* u0    = (const float*)d_in[6];
    float* out = (float*)d_out;

    // Twice on purpose: second launch overwrites out with identical values.
    abstract_leaky_relu_kernel<<<NN / 4, 256, 0, stream>>>(
        lbnd, ubnd, alpha, W, b, l0, u0, out);
    abstract_leaky_relu_kernel<<<NN / 4, 256, 0, stream>>>(
        lbnd, ubnd, alpha, W, b, l0, u0, out);
}

// Round 7
// 111.295 us; speedup vs baseline: 1.0617x; 1.0617x over previous
//
#include <hip/hip_runtime.h>

#define NN 4096
#define MM 4096
#define NEG 0.01f

typedef float v4f __attribute__((ext_vector_type(4)));

static __device__ __forceinline__ float4 nt_load4(const float* p) {
    v4f v = __builtin_nontemporal_load((const v4f*)p);
    return make_float4(v.x, v.y, v.z, v.w);
}

// Single kernel: 4 waves/block, one row of W per wave. Grid = 1024 (4/CU).
// R6b: prefetch half the W row BEFORE the LDS-staging barrier (overlaps
// prologue latency with W stream), hoist epilogue scalars to entry,
// non-temporal W loads (read-once -> don't evict c/r from L2).
__global__ __launch_bounds__(256, 4) void abstract_leaky_relu_kernel(
    const float* __restrict__ lbnd,
    const float* __restrict__ ubnd,
    const float* __restrict__ alpha,
    const float* __restrict__ W,
    const float* __restrict__ b,
    const float* __restrict__ l0,
    const float* __restrict__ u0,
    float* __restrict__ out)
{
    __shared__ float s_c[MM];
    __shared__ float s_r[MM];

    const int wave = threadIdx.x >> 6;
    const int lane = threadIdx.x & 63;
    const int row  = (blockIdx.x << 2) + wave;

    // Epilogue scalars issued at entry: latency hides under the main loop.
    const float L = lbnd[row];
    const float U = ubnd[row];
    const float A = alpha[row];
    const float B = b[row];

    const float* __restrict__ Wr = W + (size_t)row * MM;
    const int base = lane * 4;

    // Prefetch first half of this row's W before the barrier.
    float4 wpre[8];
    #pragma unroll
    for (int t = 0; t < 8; ++t)
        wpre[t] = nt_load4(Wr + base + t * 256);

    // Stage c/r into LDS (4 independent float4 sweeps per thread).
    #pragma unroll
    for (int it = 0; it < 4; ++it) {
        const int j = threadIdx.x * 4 + it * 1024;
        const float4 l = *(const float4*)(l0 + j);
        const float4 u = *(const float4*)(u0 + j);
        *(float4*)(s_c + j) = make_float4(0.5f*(l.x+u.x), 0.5f*(l.y+u.y),
                                          0.5f*(l.z+u.z), 0.5f*(l.w+u.w));
        *(float4*)(s_r + j) = make_float4(0.5f*(u.x-l.x), 0.5f*(u.y-l.y),
                                          0.5f*(u.z-l.z), 0.5f*(u.w-l.w));
    }
    __syncthreads();

    float s1a = 0.f, s1b = 0.f, s2a = 0.f, s2b = 0.f;

    // First half: consume prefetched registers (only LDS reads remain).
    #pragma unroll
    for (int t = 0; t < 8; ++t) {
        const int j = base + t * 256;
        const float4 w = wpre[t];
        const float4 c = *(const float4*)(s_c + j);
        const float4 r = *(const float4*)(s_r + j);
        if (t & 1) {
            s1b += w.x * c.x + w.y * c.y + w.z * c.z + w.w * c.w;
            s2b += fabsf(w.x) * r.x + fabsf(w.y) * r.y +
                   fabsf(w.z) * r.z + fabsf(w.w) * r.w;
        } else {
            s1a += w.x * c.x + w.y * c.y + w.z * c.z + w.w * c.w;
            s2a += fabsf(w.x) * r.x + fabsf(w.y) * r.y +
                   fabsf(w.z) * r.z + fabsf(w.w) * r.w;
        }
    }

    // Second half: streamed loads.
    #pragma unroll
    for (int t = 8; t < 16; ++t) {
        const int j = base + t * 256;
        const float4 w = nt_load4(Wr + j);
        const float4 c = *(const float4*)(s_c + j);
        const float4 r = *(const float4*)(s_r + j);
        if (t & 1) {
            s1b += w.x * c.x + w.y * c.y + w.z * c.z + w.w * c.w;
            s2b += fabsf(w.x) * r.x + fabsf(w.y) * r.y +
                   fabsf(w.z) * r.z + fabsf(w.w) * r.w;
        } else {
            s1a += w.x * c.x + w.y * c.y + w.z * c.z + w.w * c.w;
            s2a += fabsf(w.x) * r.x + fabsf(w.y) * r.y +
                   fabsf(w.z) * r.z + fabsf(w.w) * r.w;
        }
    }

    float s1 = s1a + s1b;
    float s2 = s2a + s2b;

    #pragma unroll
    for (int off = 32; off > 0; off >>= 1) {
        s1 += __shfl_down(s1, off);
        s2 += __shfl_down(s2, off);
    }

    if (lane == 0) {
        float lw = NEG, uw = NEG, ub_bias = 0.0f;
        if (L > 0.0f) {
            lw = 1.0f; uw = 1.0f;
        } else if (L < 0.0f && U > 0.0f) {
            const float slope = (U - NEG * L) / (U - L);
            uw = slope;
            ub_bias = (NEG - slope) * L;   // crossing-neuron upper intercept
            lw = fminf(fmaxf(A, NEG), 1.0f);
        }

        const float Pu = s1 + s2;   // max(W,0)@u0 + min(W,0)@l0
        const float Pl = s1 - s2;   // max(W,0)@l0 + min(W,0)@u0
        out[row]      = lw * (Pl + B);             // lower
        out[NN + row] = uw * (Pu + B) + ub_bias;   // upper
    }
}

extern "C" void kernel_launch(void* const* d_in, const int* in_sizes, int n_in,
                              void* d_out, int out_size, void* d_ws, size_t ws_size,
                              hipStream_t stream) {
    const float* lbnd  = (const float*)d_in[0];
    const float* ubnd  = (const float*)d_in[1];
    const float* alpha = (const float*)d_in[2];
    const float* W     = (const float*)d_in[3];
    const float* b     = (const float*)d_in[4];
    const float* l0    = (const float*)d_in[5];
    const float* u0    = (const float*)d_in[6];
    float* out = (float*)d_out;

    abstract_leaky_relu_kernel<<<NN / 4, 256, 0, stream>>>(
        lbnd, ubnd, alpha, W, b, l0, u0, out);
}

// Round 8
// 107.492 us; speedup vs baseline: 1.0993x; 1.0354x over previous
//
#include <hip/hip_runtime.h>

#define NN 4096
#define MM 4096
#define NEG 0.01f

// R8: no LDS, no barrier, no prologue. l0/u0 (16 KB each) are read directly
// in the main loop as cached loads — they fit in L1 and broadcast across all
// waves; W streams from HBM/L3 with plain (cache-friendly) float4 loads.
// The 0.5 factor of c=(l+u)/2, r=(u-l)/2 is folded into the epilogue.
// Grid = 1024 blocks x 256 threads (4 waves/block, 1 row/wave, 4 blocks/CU).
__global__ __launch_bounds__(256, 4) void abstract_leaky_relu_kernel(
    const float* __restrict__ lbnd,
    const float* __restrict__ ubnd,
    const float* __restrict__ alpha,
    const float* __restrict__ W,
    const float* __restrict__ b,
    const float* __restrict__ l0,
    const float* __restrict__ u0,
    float* __restrict__ out)
{
    const int wave = threadIdx.x >> 6;
    const int lane = threadIdx.x & 63;
    const int row  = (blockIdx.x << 2) + wave;

    // Epilogue scalars issued at entry: latency hides under the main loop.
    const float L = lbnd[row];
    const float U = ubnd[row];
    const float A = alpha[row];
    const float B = b[row];

    const float* __restrict__ Wr = W + (size_t)row * MM;
    const int base = lane * 4;

    float s1a = 0.f, s1b = 0.f, s2a = 0.f, s2b = 0.f;

    #pragma unroll
    for (int t = 0; t < 16; ++t) {
        const int j = base + t * 256;
        const float4 w = *(const float4*)(Wr + j);
        const float4 l = *(const float4*)(l0 + j);
        const float4 u = *(const float4*)(u0 + j);
        // c' = l+u (2c), r' = u-l (2r); 0.5 applied after reduction.
        if (t & 1) {
            s1b += w.x * (l.x + u.x) + w.y * (l.y + u.y) +
                   w.z * (l.z + u.z) + w.w * (l.w + u.w);
            s2b += fabsf(w.x) * (u.x - l.x) + fabsf(w.y) * (u.y - l.y) +
                   fabsf(w.z) * (u.z - l.z) + fabsf(w.w) * (u.w - l.w);
        } else {
            s1a += w.x * (l.x + u.x) + w.y * (l.y + u.y) +
                   w.z * (l.z + u.z) + w.w * (l.w + u.w);
            s2a += fabsf(w.x) * (u.x - l.x) + fabsf(w.y) * (u.y - l.y) +
                   fabsf(w.z) * (u.z - l.z) + fabsf(w.w) * (u.w - l.w);
        }
    }

    float s1 = s1a + s1b;
    float s2 = s2a + s2b;

    #pragma unroll
    for (int off = 32; off > 0; off >>= 1) {
        s1 += __shfl_down(s1, off);
        s2 += __shfl_down(s2, off);
    }

    if (lane == 0) {
        s1 *= 0.5f;   // deferred c = (l+u)/2
        s2 *= 0.5f;   // deferred r = (u-l)/2

        float lw = NEG, uw = NEG, ub_bias = 0.0f;
        if (L > 0.0f) {
            lw = 1.0f; uw = 1.0f;
        } else if (L < 0.0f && U > 0.0f) {
            const float slope = (U - NEG * L) / (U - L);
            uw = slope;
            ub_bias = (NEG - slope) * L;   // crossing-neuron upper intercept
            lw = fminf(fmaxf(A, NEG), 1.0f);
        }

        const float Pu = s1 + s2;   // max(W,0)@u0 + min(W,0)@l0
        const float Pl = s1 - s2;   // max(W,0)@l0 + min(W,0)@u0
        out[row]      = lw * (Pl + B);             // lower
        out[NN + row] = uw * (Pu + B) + ub_bias;   // upper
    }
}

extern "C" void kernel_launch(void* const* d_in, const int* in_sizes, int n_in,
                              void* d_out, int out_size, void* d_ws, size_t ws_size,
                              hipStream_t stream) {
    const float* lbnd  = (const float*)d_in[0];
    const float* ubnd  = (const float*)d_in[1];
    const float* alpha = (const float*)d_in[2];
    const float* W     = (const float*)d_in[3];
    const float* b     = (const float*)d_in[4];
    const float* l0    = (const float*)d_in[5];
    const float* u0    = (const float*)d_in[6];
    float* out = (float*)d_out;

    abstract_leaky_relu_kernel<<<NN / 4, 256, 0, stream>>>(
        lbnd, ubnd, alpha, W, b, l0, u0, out);
}

// Round 9
// 104.460 us; speedup vs baseline: 1.1312x; 1.0290x over previous
//
#include <hip/hip_runtime.h>

#define NN 4096
#define MM 4096
#define NEG 0.01f

// BEST-KNOWN (R4): single kernel, 4 waves/block, one row of W per wave.
// Grid = 1024 blocks -> 4 blocks/CU, 16 waves/CU.
// LDS-staged c/r (separate lgkmcnt pipe; keeps the hot loop at ONE vmem
// instruction per t — R8 showed 3 vmem/t throttles the W stream).
// Fully unrolled 16x independent float4 W loads, dual accumulator pairs.
__global__ __launch_bounds__(256, 4) void abstract_leaky_relu_kernel(
    const float* __restrict__ lbnd,
    const float* __restrict__ ubnd,
    const float* __restrict__ alpha,
    const float* __restrict__ W,
    const float* __restrict__ b,
    const float* __restrict__ l0,
    const float* __restrict__ u0,
    float* __restrict__ out)
{
    __shared__ float s_c[MM];
    __shared__ float s_r[MM];

    for (int j = threadIdx.x * 4; j < MM; j += 256 * 4) {
        const float4 l = *(const float4*)(l0 + j);
        const float4 u = *(const float4*)(u0 + j);
        *(float4*)(s_c + j) = make_float4(0.5f*(l.x+u.x), 0.5f*(l.y+u.y),
                                          0.5f*(l.z+u.z), 0.5f*(l.w+u.w));
        *(float4*)(s_r + j) = make_float4(0.5f*(u.x-l.x), 0.5f*(u.y-l.y),
                                          0.5f*(u.z-l.z), 0.5f*(u.w-l.w));
    }
    __syncthreads();

    const int wave = threadIdx.x >> 6;
    const int lane = threadIdx.x & 63;
    const int row  = (blockIdx.x << 2) + wave;

    const float* __restrict__ Wr = W + (size_t)row * MM;
    const int base = lane * 4;

    float s1a = 0.f, s1b = 0.f, s2a = 0.f, s2b = 0.f;

    #pragma unroll
    for (int t = 0; t < 16; ++t) {
        const int j = base + t * 256;
        const float4 w = *(const float4*)(Wr + j);
        const float4 c = *(const float4*)(s_c + j);
        const float4 r = *(const float4*)(s_r + j);
        if (t & 1) {
            s1b += w.x * c.x + w.y * c.y + w.z * c.z + w.w * c.w;
            s2b += fabsf(w.x) * r.x + fabsf(w.y) * r.y +
                   fabsf(w.z) * r.z + fabsf(w.w) * r.w;
        } else {
            s1a += w.x * c.x + w.y * c.y + w.z * c.z + w.w * c.w;
            s2a += fabsf(w.x) * r.x + fabsf(w.y) * r.y +
                   fabsf(w.z) * r.z + fabsf(w.w) * r.w;
        }
    }

    float s1 = s1a + s1b;
    float s2 = s2a + s2b;

    #pragma unroll
    for (int off = 32; off > 0; off >>= 1) {
        s1 += __shfl_down(s1, off);
        s2 += __shfl_down(s2, off);
    }

    if (lane == 0) {
        const float L = lbnd[row];
        const float U = ubnd[row];
        const float A = alpha[row];
        const float B = b[row];

        float lw = NEG, uw = NEG, ub_bias = 0.0f;
        if (L > 0.0f) {
            lw = 1.0f; uw = 1.0f;
        } else if (L < 0.0f && U > 0.0f) {
            const float slope = (U - NEG * L) / (U - L);
            uw = slope;
            ub_bias = (NEG - slope) * L;   // crossing-neuron upper intercept
            lw = fminf(fmaxf(A, NEG), 1.0f);
        }

        const float Pu = s1 + s2;   // max(W,0)@u0 + min(W,0)@l0
        const float Pl = s1 - s2;   // max(W,0)@l0 + min(W,0)@u0
        out[row]      = lw * (Pl + B);             // lower
        out[NN + row] = uw * (Pu + B) + ub_bias;   // upper
    }
}

extern "C" void kernel_launch(void* const* d_in, const int* in_sizes, int n_in,
                              void* d_out, int out_size, void* d_ws, size_t ws_size,
                              hipStream_t stream) {
    const float* lbnd  = (const float*)d_in[0];
    const float* ubnd  = (const float*)d_in[1];
    const float* alpha = (const float*)d_in[2];
    const float* W     = (const float*)d_in[3];
    const float* b     = (const float*)d_in[4];
    const float* l0    = (const float*)d_in[5];
    const float* u0    = (const float*)d_in[6];
    float* out = (float*)d_out;

    abstract_leaky_relu_kernel<<<NN / 4, 256, 0, stream>>>(
        lbnd, ubnd, alpha, W, b, l0, u0, out);
}